// Round 6
// baseline (1074.099 us; speedup 1.0000x reference)
//
#include <hip/hip_runtime.h>

#define BB 8
#define TT 160
#define EE 300
#define HH 128
#define D2 256
#define G3 384

typedef __attribute__((ext_vector_type(8))) short bf16x8;
typedef __attribute__((ext_vector_type(4))) float floatx4;

__device__ inline float fsigmoid(float x){ return 1.f/(1.f+__expf(-x)); }
__device__ inline float ftanh(float x){ return 2.f*fsigmoid(2.f*x) - 1.f; }

// truncation split: x ~= hi + lo, each bf16; combined rel err <= ~2^-16
__device__ inline void split2(float x, unsigned short& hi, unsigned short& lo){
  unsigned ux = __float_as_uint(x);
  hi = (unsigned short)(ux>>16);
  float r = x - __uint_as_float(ux & 0xFFFF0000u);
  lo = (unsigned short)(__float_as_uint(r)>>16);
}

// ---------------- embedding gather (fp32 emb) ----------------
__global__ __launch_bounds__(256) void k_embed(const int* ta, const int* tb,
    const float* emb, float* ep, float* ec){
  const int idx = blockIdx.x*256 + threadIdx.x;
  const int per = BB*TT*EE;
  if (idx < per){
    const int e = idx % EE, bt = idx / EE;
    ep[idx] = emb[(long)ta[bt]*EE + e];
  } else {
    const int j = idx - per;
    const int e = j % EE, bt = j / EE;
    ec[j] = emb[(long)tb[bt]*EE + e];
  }
}

// ---------------- hi/lo bf16 split of hp & hc (for pairattn B-operand) ----------------
__global__ __launch_bounds__(256) void k_splitarr(const float* a, const float* b, int n,
    unsigned short* ahi, unsigned short* alo, unsigned short* bhi, unsigned short* blo){
  const int idx = blockIdx.x*256 + threadIdx.x;
  if (idx < n){
    split2(a[idx], ahi[idx], alo[idx]);
    split2(b[idx], bhi[idx], blo[idx]);
  }
}

// ---------------- MFMA GEMM: C[M x N] = A[M x K](f32) @ W[N x K](f32)^T + bias ----------------
// 64x64 tile per 256-thread block; fp32 emulated via bf16 hi/lo split, 3 MFMA passes.
struct GemmJob {
  const float* A; const float* W; const float* bias;
  float* C; int N; int K;
};
struct GemmJobs { GemmJob j[6]; };

__global__ __launch_bounds__(256) void k_gemm(GemmJobs jobs){
  const GemmJob J = jobs.j[blockIdx.z];
  const int tid = threadIdx.x;
  const int lane = tid & 63, w = tid >> 6;
  const int l15 = lane & 15, q = lane >> 4;
  const int n0 = blockIdx.x * 64;
  if (n0 >= J.N) return;
  const int K = J.K;
  const long mrow = blockIdx.y*64 + w*16 + l15;
  const float* Arow = J.A + mrow*K;
  floatx4 acc[4];
  #pragma unroll
  for (int t=0;t<4;t++) acc[t] = (floatx4)0.f;
  const int nch = (K+31)>>5;
  for (int kc=0; kc<nch; kc++){
    const int k0 = kc<<5;
    const int kb = k0 + q*8;
    const bool full = (k0+32 <= K);
    float av[8];
    if (full){
      const floatx4 a0 = *(const floatx4*)(Arow+kb);
      const floatx4 a1 = *(const floatx4*)(Arow+kb+4);
      av[0]=a0[0];av[1]=a0[1];av[2]=a0[2];av[3]=a0[3];
      av[4]=a1[0];av[5]=a1[1];av[6]=a1[2];av[7]=a1[3];
    } else {
      #pragma unroll
      for (int j=0;j<8;j++){ const int k=kb+j; av[j] = (k<K)? Arow[k] : 0.f; }
    }
    union { bf16x8 v; unsigned short u[8]; } ahi, alo;
    #pragma unroll
    for (int j=0;j<8;j++) split2(av[j], ahi.u[j], alo.u[j]);
    #pragma unroll
    for (int t=0;t<4;t++){
      const int n = n0 + t*16 + l15;
      const float* Wr = J.W + (long)n*K + kb;
      float wv[8];
      if (full){
        const floatx4 w0 = *(const floatx4*)(Wr);
        const floatx4 w1 = *(const floatx4*)(Wr+4);
        wv[0]=w0[0];wv[1]=w0[1];wv[2]=w0[2];wv[3]=w0[3];
        wv[4]=w1[0];wv[5]=w1[1];wv[6]=w1[2];wv[7]=w1[3];
      } else {
        #pragma unroll
        for (int j=0;j<8;j++){ const int k=kb+j; wv[j] = (k<K)? Wr[j] : 0.f; }
      }
      union { bf16x8 v; unsigned short u[8]; } whi, wlo;
      #pragma unroll
      for (int j=0;j<8;j++) split2(wv[j], whi.u[j], wlo.u[j]);
      acc[t] = __builtin_amdgcn_mfma_f32_16x16x32_bf16(ahi.v, whi.v, acc[t], 0,0,0);
      acc[t] = __builtin_amdgcn_mfma_f32_16x16x32_bf16(ahi.v, wlo.v, acc[t], 0,0,0);
      acc[t] = __builtin_amdgcn_mfma_f32_16x16x32_bf16(alo.v, whi.v, acc[t], 0,0,0);
    }
  }
  const long rbase = blockIdx.y*64 + w*16 + q*4;
  #pragma unroll
  for (int t=0;t<4;t++){
    const int n = n0 + t*16 + l15;
    const float bv = J.bias ? J.bias[n] : 0.f;
    #pragma unroll
    for (int r=0;r<4;r++)
      J.C[(rbase+r)*(long)J.N + n] = acc[t][r] + bv;
  }
}

// ---------------- GRU scan: 768 threads, 2 threads per gate; xt prefetch ----------------
struct GruJob { const float* xg; const float* Whh; const float* bhh; float* out; int ocol; int rev; };
struct GruJobs { GruJob j[4]; };

__global__ __launch_bounds__(768) void k_gru(GruJobs jobs){
  const GruJob J = jobs.j[blockIdx.y];
  const int bi = blockIdx.x;
  const int tid = threadIdx.x;
  const int g = tid >> 1, p = tid & 1;   // gate, half
  __shared__ float h_sh[HH];
  __shared__ float gh_sh[G3];
  __shared__ float xt_sh[G3];
  float wr[64];
  {
    const float* wp = J.Whh + (long)g*HH + p*64;
    #pragma unroll
    for (int k=0;k<64;k+=4){
      const floatx4 t4 = *(const floatx4*)(wp+k);
      wr[k]=t4[0]; wr[k+1]=t4[1]; wr[k+2]=t4[2]; wr[k+3]=t4[3];
    }
  }
  const float bhh = J.bhh[g];
  if (tid < HH) h_sh[tid] = 0.f;
  float hreg = 0.f;
  float xv = 0.f;
  {
    const int t0 = J.rev ? (TT-1) : 0;
    if (tid < G3) xv = J.xg[((long)bi*TT + t0)*G3 + tid];
  }
  __syncthreads();
  for (int t=0;t<TT;t++){
    const int tt = J.rev ? (TT-1-t) : t;
    if (tid < G3) xt_sh[tid] = xv;
    if (t+1 < TT){
      const int tn = J.rev ? (TT-2-t) : (t+1);
      if (tid < G3) xv = J.xg[((long)bi*TT + tn)*G3 + tid];
    }
    float gh = 0.f;
    #pragma unroll
    for (int k=0;k<64;k+=4){
      const floatx4 h4 = *(const floatx4*)&h_sh[p*64 + k];
      gh += wr[k]*h4[0] + wr[k+1]*h4[1] + wr[k+2]*h4[2] + wr[k+3]*h4[3];
    }
    gh += __shfl_xor(gh, 1);
    if (p==0) gh_sh[g] = gh + bhh;
    __syncthreads();
    if (tid < HH){
      const float r = fsigmoid(xt_sh[tid]       + gh_sh[tid]);
      const float z = fsigmoid(xt_sh[tid+HH]    + gh_sh[tid+HH]);
      const float n = ftanh  (xt_sh[tid+2*HH]  + r*gh_sh[tid+2*HH]);
      const float h = (1.f-z)*n + z*hreg;
      hreg = h;
      h_sh[tid] = h;
      J.out[((long)bi*TT + tt)*D2 + J.ocol + tid] = h;
    }
    __syncthreads();
  }
}

// ---------------- block softmax over 160 values (256 threads) ----------------
__device__ inline float block_softmax160(float s, int tid, float* red){
  float m = s;
  #pragma unroll
  for (int o=32;o>0;o>>=1) m = fmaxf(m, __shfl_xor(m,o));
  if ((tid&63)==0) red[tid>>6] = m;
  __syncthreads();
  m = fmaxf(fmaxf(red[0],red[1]), fmaxf(red[2],red[3]));
  const float p = (tid<TT) ? __expf(s-m) : 0.f;
  float t = p;
  #pragma unroll
  for (int o=32;o>0;o>>=1) t += __shfl_xor(t,o);
  if ((tid&63)==0) red[4+(tid>>6)] = t;
  __syncthreads();
  const float sum = red[4]+red[5]+red[6]+red[7];
  return p / sum;
}

// ---------------- pairwise product attention (dot & self) via MFMA ----------------
// score[b,c,t] = sum_h V[h] * tanh( sum_d (W[h,d]*Q[c,d]) * P[t,d] )
// A-side = WQ (fp32 product, exact hi/lo split, c-dependent, only h x d work)
// B-side = P pre-split hi/lo bf16 (global, c-invariant)
struct PairJob { const unsigned short* Phi; const unsigned short* Plo;
                 const float* Q; const float* W; const float* V; float* a_out; };

__global__ __launch_bounds__(256) void k_pairattn(PairJob j0, PairJob j1){
  const PairJob J = blockIdx.z ? j1 : j0;
  const int b = blockIdx.y, c = blockIdx.x;
  const int tid = threadIdx.x, lane = tid&63, w = tid>>6;
  const int l15 = lane&15, q = lane>>4;
  __shared__ float sc_sh[TT];
  __shared__ float red[8];
  if (tid < TT) sc_sh[tid] = 0.f;
  __syncthreads();
  const float* Qrow = J.Q + ((long)b*TT + c)*D2;
  floatx4 acc[2][10];
  #pragma unroll
  for (int i=0;i<2;i++)
    #pragma unroll
    for (int nt=0;nt<10;nt++) acc[i][nt] = (floatx4)0.f;
  for (int kc=0;kc<8;kc++){
    const int d0 = kc*32 + q*8;
    const floatx4 q0 = *(const floatx4*)(Qrow + d0);
    const floatx4 q1 = *(const floatx4*)(Qrow + d0 + 4);
    union { bf16x8 v; unsigned short u[8]; } ah[2], al[2];
    #pragma unroll
    for (int i=0;i<2;i++){
      const float* Wr = J.W + ((long)((2*w+i)*16 + l15))*D2 + d0;
      const floatx4 w0 = *(const floatx4*)(Wr);
      const floatx4 w1 = *(const floatx4*)(Wr+4);
      #pragma unroll
      for (int j=0;j<4;j++){
        split2(w0[j]*q0[j], ah[i].u[j],   al[i].u[j]);
        split2(w1[j]*q1[j], ah[i].u[4+j], al[i].u[4+j]);
      }
    }
    #pragma unroll
    for (int nt=0;nt<10;nt++){
      const long prow = ((long)b*TT + nt*16 + l15)*D2 + d0;
      union { bf16x8 v; uint4 d; } bh, bl;
      bh.d = *(const uint4*)(J.Phi + prow);
      bl.d = *(const uint4*)(J.Plo + prow);
      #pragma unroll
      for (int i=0;i<2;i++){
        acc[i][nt] = __builtin_amdgcn_mfma_f32_16x16x32_bf16(ah[i].v, bh.v, acc[i][nt], 0,0,0);
        acc[i][nt] = __builtin_amdgcn_mfma_f32_16x16x32_bf16(ah[i].v, bl.v, acc[i][nt], 0,0,0);
        acc[i][nt] = __builtin_amdgcn_mfma_f32_16x16x32_bf16(al[i].v, bh.v, acc[i][nt], 0,0,0);
      }
    }
  }
  float vreg[2][4];
  #pragma unroll
  for (int i=0;i<2;i++)
    #pragma unroll
    for (int r=0;r<4;r++) vreg[i][r] = J.V[(2*w+i)*16 + q*4 + r];
  #pragma unroll
  for (int nt=0;nt<10;nt++){
    float pp = 0.f;
    #pragma unroll
    for (int i=0;i<2;i++)
      #pragma unroll
      for (int r=0;r<4;r++)
        pp += vreg[i][r]*ftanh(acc[i][nt][r]);
    pp += __shfl_xor(pp,16);
    pp += __shfl_xor(pp,32);
    if (q==0) atomicAdd(&sc_sh[nt*16 + l15], pp);
  }
  __syncthreads();
  const float s = (tid<TT)? sc_sh[tid] : -INFINITY;
  const float a = block_softmax160(s, tid, red);
  if (tid < TT) J.a_out[((long)b*TT + c)*TT + tid] = a;
}

// ---------------- additive attentions (concat / minus) ----------------
struct AddJob { const float* up; const float* uc; const float* V; float sgn; float* a_out; };

__global__ __launch_bounds__(256) void k_addattn(AddJob j0, AddJob j1){
  const AddJob J = blockIdx.z ? j1 : j0;
  const int b = blockIdx.y, c = blockIdx.x, tid = threadIdx.x;
  __shared__ float ucc[HH];
  __shared__ float vv[HH];
  __shared__ float red[8];
  if (tid < HH){
    ucc[tid] = J.sgn * J.uc[((long)b*TT + c)*HH + tid];
    vv[tid] = J.V[tid];
  }
  __syncthreads();
  float s = -INFINITY;
  if (tid < TT){
    const float* ur = J.up + ((long)b*TT + tid)*HH;
    float a0 = 0.f;
    #pragma unroll 4
    for (int k=0;k<HH;k++) a0 += vv[k]*ftanh(ur[k]+ucc[k]);
    s = a0;
  }
  const float a = block_softmax160(s, tid, red);
  if (tid < TT) J.a_out[((long)b*TT + c)*TT + tid] = a;
}

// ---------------- bilinear attention ----------------
__global__ __launch_bounds__(256) void k_bilattn(const float* hc, const float* hpWb, float* a_out){
  const int b = blockIdx.y, c = blockIdx.x, tid = threadIdx.x;
  __shared__ float hcc[D2];
  __shared__ float red[8];
  if (tid < D2) hcc[tid] = hc[((long)b*TT + c)*D2 + tid];
  __syncthreads();
  float s = -INFINITY;
  if (tid < TT){
    const float* pr = hpWb + ((long)b*TT + tid)*D2;
    float a0 = 0.f;
    #pragma unroll 4
    for (int k=0;k<D2;k++) a0 += hcc[k]*pr[k];
    s = a0;
  }
  const float a = block_softmax160(s, tid, red);
  if (tid < TT) a_out[((long)b*TT + c)*TT + tid] = a;
}

// ---------------- rep build ----------------
__global__ __launch_bounds__(256) void k_rep(const float* hp, const float* hc,
    const float* acat, const float* abil, const float* adot, const float* amin, const float* aself,
    float* aggin){
  const int b = blockIdx.y, c = blockIdx.x, tid = threadIdx.x;
  __shared__ float a5[5][TT];
  {
    const long base = ((long)b*TT + c)*TT;
    for (int i=tid;i<5*TT;i+=256){
      const int which = i/TT, t = i - which*TT;
      const float* p = which==0? acat : which==1? abil : which==2? adot : which==3? amin : aself;
      a5[which][t] = p[base + t];
    }
  }
  __syncthreads();
  const float* hpb = hp + (long)b*TT*D2 + tid;
  const float* hcb = hc + (long)b*TT*D2 + tid;
  float r0=0.f,r1=0.f,r2=0.f,r3=0.f,r4=0.f;
  for (int t=0;t<TT;t++){
    const float vp = hpb[(long)t*D2];
    const float vc = hcb[(long)t*D2];
    r0 += a5[0][t]*vp;
    r1 += a5[1][t]*vp;
    r2 += a5[2][t]*vp;
    r3 += a5[3][t]*vp;
    r4 += a5[4][t]*vc;
  }
  float* o = aggin + ((long)b*TT + c)*(6*D2);
  o[tid]        = hc[((long)b*TT + c)*D2 + tid];
  o[D2 + tid]   = r4;
  o[2*D2 + tid] = r0;
  o[3*D2 + tid] = r2;
  o[4*D2 + tid] = r1;
  o[5*D2 + tid] = r3;
}

// ---------------- tail1 ----------------
__global__ __launch_bounds__(256) void k_tail1(const float* upP, const float* Vp,
    const float* hp, float* rp){
  const int b = blockIdx.x, tid = threadIdx.x;
  __shared__ float vv[HH];
  __shared__ float ap_sh[TT];
  __shared__ float red[8];
  if (tid<HH) vv[tid] = Vp[tid];
  __syncthreads();
  float s = -INFINITY;
  if (tid<TT){
    const float* ur = upP + ((long)b*TT + tid)*HH;
    float a0=0.f;
    #pragma unroll 4
    for (int k=0;k<HH;k++) a0 += vv[k]*ftanh(ur[k]);
    s = a0;
  }
  const float a = block_softmax160(s, tid, red);
  if (tid<TT) ap_sh[tid] = a;
  __syncthreads();
  float acc = 0.f;
  const float* hpb = hp + (long)b*TT*D2 + tid;
  for (int t=0;t<TT;t++) acc += ap_sh[t]*hpb[(long)t*D2];
  rp[b*D2 + tid] = acc;
}

// ---------------- tail2 ----------------
__global__ __launch_bounds__(256) void k_tail2(const float* aggW1, const float* agg, const float* rp,
    const float* W2, const float* Vv, const float* Wout, const float* bout,
    float* out){
  const int b = blockIdx.x, tid = threadIdx.x;
  __shared__ float rpw[HH];
  __shared__ float ac_sh[TT];
  __shared__ float rc_sh[D2];
  __shared__ float red[8];
  if (tid < HH){
    float a0=0.f;
    const float* wr2 = W2 + (long)tid*D2;
    const float* rr = rp + b*D2;
    for (int d=0; d<D2; d++) a0 += wr2[d]*rr[d];
    rpw[tid] = a0;
  }
  __syncthreads();
  float s = -INFINITY;
  if (tid < TT){
    const float* ar = aggW1 + ((long)b*TT + tid)*HH;
    float a0=0.f;
    for (int k=0;k<HH;k++) a0 += Vv[k]*(ar[k] + rpw[k]);
    s = a0;
  }
  const float a = block_softmax160(s, tid, red);
  if (tid < TT) ac_sh[tid] = a;
  __syncthreads();
  float rc=0.f;
  const float* ab = agg + (long)b*TT*D2 + tid;
  for (int t=0;t<TT;t++) rc += ac_sh[t]*ab[(long)t*D2];
  rc_sh[tid] = rc;
  __syncthreads();
  if (tid < 2){
    float o = bout[tid];
    const float* wr = Wout + (long)tid*D2;
    for (int d=0; d<D2; d++) o += wr[d]*rc_sh[d];
    out[b*2 + tid] = o;
  }
}

extern "C" void kernel_launch(void* const* d_in, const int* in_sizes, int n_in,
                              void* d_out, int out_size, void* d_ws, size_t ws_size,
                              hipStream_t stream){
  (void)in_sizes; (void)n_in; (void)out_size; (void)ws_size;
  const int* ta = (const int*)d_in[0];
  const int* tb = (const int*)d_in[1];
  const float* emb = (const float*)d_in[2];
  #define F32(i) ((const float*)d_in[i])

  float* ws = (float*)d_ws;
  float* ep    = ws;                 // 8*160*300
  float* ec    = ep    + 384000;
  float* xg_pf = ec    + 384000;     // 8*160*384 each; reused by agg stage later
  float* xg_pb = xg_pf + 491520;
  float* xg_cf = xg_pb + 491520;
  float* xg_cb = xg_cf + 491520;
  float* hp    = xg_cb + 491520;     // 8*160*256
  float* hc    = hp    + 327680;
  float* up1   = hc    + 327680;     // 8*160*128 each
  float* uc2   = up1   + 163840;
  float* ump   = uc2   + 163840;
  float* umc   = ump   + 163840;
  float* upP   = umc   + 163840;
  float* hpWb  = upP   + 163840;     // 8*160*256
  float* acat  = hpWb  + 327680;     // 8*160*160 each
  float* abil  = acat  + 204800;
  float* adot  = abil  + 204800;
  float* amin  = adot  + 204800;
  float* aself = amin  + 204800;
  float* aggin = aself + 204800;     // 8*160*1536
  float* rp    = aggin + 1966080;    // 8*256
  unsigned short* hp_hi = (unsigned short*)(rp + 2048);   // 327680 u16 each
  unsigned short* hp_lo = hp_hi + 327680;
  unsigned short* hc_hi = hp_lo + 327680;
  unsigned short* hc_lo = hc_hi + 327680;
  // dead-buffer reuse for the agg stage:
  float* xg_af = xg_pf;              // dead after p/c GRU
  float* xg_ab = xg_pb;
  float* agg   = xg_cf;              // 327680 <= 491520
  float* aggW1 = xg_cb;              // 163840 <= 491520

  // 1) embedding gather
  k_embed<<<dim3(3000), dim3(256), 0, stream>>>(ta, tb, emb, ep, ec);

  // 2) xg = x @ Wih^T + bih for p/c  (M=1280, N=384, K=300)
  GemmJobs ja = {};
  ja.j[0] = {ep, F32(3),  F32(5),  xg_pf, 384, 300};
  ja.j[1] = {ep, F32(7),  F32(9),  xg_pb, 384, 300};
  ja.j[2] = {ec, F32(11), F32(13), xg_cf, 384, 300};
  ja.j[3] = {ec, F32(15), F32(17), xg_cb, 384, 300};
  k_gemm<<<dim3(6,20,4), dim3(256), 0, stream>>>(ja);

  // 3) p/c GRU scans
  GruJobs gj = {};
  gj.j[0] = {xg_pf, F32(4),  F32(6),  hp, 0,   0};
  gj.j[1] = {xg_pb, F32(8),  F32(10), hp, 128, 1};
  gj.j[2] = {xg_cf, F32(12), F32(14), hc, 0,   0};
  gj.j[3] = {xg_cb, F32(16), F32(18), hc, 128, 1};
  k_gru<<<dim3(8,4), dim3(768), 0, stream>>>(gj);

  // 3b) hi/lo split of hp & hc for pairattn B-operands
  k_splitarr<<<dim3(1280), dim3(256), 0, stream>>>(hp, hc, 327680, hp_hi, hp_lo, hc_hi, hc_lo);

  // 4) projection GEMMs (N=128 or 256, K=256)
  GemmJobs jb = {};
  jb.j[0] = {hp, F32(27), nullptr, up1,  128, 256};
  jb.j[1] = {hc, F32(28), nullptr, uc2,  128, 256};
  jb.j[2] = {hp, F32(33), nullptr, ump,  128, 256};
  jb.j[3] = {hc, F32(33), nullptr, umc,  128, 256};
  jb.j[4] = {hp, F32(37), nullptr, upP,  128, 256};
  jb.j[5] = {hp, F32(30), nullptr, hpWb, 256, 256};
  k_gemm<<<dim3(4,20,6), dim3(256), 0, stream>>>(jb);

  // 5) dot & self attentions (MFMA, A=W*Q exact-split, B=P pre-split)
  PairJob pd  = {hp_hi, hp_lo, hc, F32(31), F32(32), adot};
  PairJob psf = {hc_hi, hc_lo, hc, F32(35), F32(36), aself};
  k_pairattn<<<dim3(160,8,2), dim3(256), 0, stream>>>(pd, psf);

  // 6) concat & minus attentions
  AddJob ac_ = {up1, uc2, F32(29),  1.f, acat};
  AddJob am_ = {ump, umc, F32(34), -1.f, amin};
  k_addattn<<<dim3(160,8,2), dim3(256), 0, stream>>>(ac_, am_);

  // 7) bilinear attention
  k_bilattn<<<dim3(160,8), dim3(256), 0, stream>>>(hc, hpWb, abil);

  // 8) ap/rp pooling
  k_tail1<<<dim3(8), dim3(256), 0, stream>>>(upP, F32(38), hp, rp);

  // 9) weighted reps -> agg_in
  k_rep<<<dim3(160,8), dim3(256), 0, stream>>>(hp, hc, acat, abil, adot, amin, aself, aggin);

  // 10) agg xg GEMMs (M=1280, N=384, K=1536)
  GemmJobs jc = {};
  jc.j[0] = {aggin, F32(19), F32(21), xg_af, 384, 1536};
  jc.j[1] = {aggin, F32(23), F32(25), xg_ab, 384, 1536};
  k_gemm<<<dim3(6,20,2), dim3(256), 0, stream>>>(jc);

  // 11) agg GRU scans
  GruJobs gja = {};
  gja.j[0] = {xg_af, F32(20), F32(22), agg, 0,   0};
  gja.j[1] = {xg_ab, F32(24), F32(26), agg, 128, 1};
  k_gru<<<dim3(8,2), dim3(768), 0, stream>>>(gja);

  // 12) agg @ W1^T (N=128, K=256)
  GemmJobs jd = {};
  jd.j[0] = {agg, F32(39), nullptr, aggW1, 128, 256};
  k_gemm<<<dim3(2,20,1), dim3(256), 0, stream>>>(jd);

  // 13) final scores + output
  k_tail2<<<dim3(8), dim3(256), 0, stream>>>(aggW1, agg, rp, F32(40), F32(41), F32(42), F32(43),
                                             (float*)d_out);
  #undef F32
}

// Round 7
// 927.485 us; speedup vs baseline: 1.1581x; 1.1581x over previous
//
#include <hip/hip_runtime.h>

#define BB 8
#define TT 160
#define EE 300
#define HH 128
#define D2 256
#define G3 384
#define PSTR 40   // padded LDS row stride (shorts) for P tiles: 2-way-free bank pattern

typedef __attribute__((ext_vector_type(8))) short bf16x8;
typedef __attribute__((ext_vector_type(4))) float floatx4;

__device__ inline float fsigmoid(float x){ return 1.f/(1.f+__expf(-x)); }
__device__ inline float ftanh(float x){ return 2.f*fsigmoid(2.f*x) - 1.f; }

// truncation split: x ~= hi + lo, each bf16; combined rel err <= ~2^-16
__device__ inline void split2(float x, unsigned short& hi, unsigned short& lo){
  unsigned ux = __float_as_uint(x);
  hi = (unsigned short)(ux>>16);
  float r = x - __uint_as_float(ux & 0xFFFF0000u);
  lo = (unsigned short)(__float_as_uint(r)>>16);
}

// ---------------- embedding gather (fp32 emb) ----------------
__global__ __launch_bounds__(256) void k_embed(const int* ta, const int* tb,
    const float* emb, float* ep, float* ec){
  const int idx = blockIdx.x*256 + threadIdx.x;
  const int per = BB*TT*EE;
  if (idx < per){
    const int e = idx % EE, bt = idx / EE;
    ep[idx] = emb[(long)ta[bt]*EE + e];
  } else {
    const int j = idx - per;
    const int e = j % EE, bt = j / EE;
    ec[j] = emb[(long)tb[bt]*EE + e];
  }
}

// ---------------- hi/lo bf16 split of hp & hc (for pairattn B-operand) ----------------
__global__ __launch_bounds__(256) void k_splitarr(const float* a, const float* b, int n,
    unsigned short* ahi, unsigned short* alo, unsigned short* bhi, unsigned short* blo){
  const int idx = blockIdx.x*256 + threadIdx.x;
  if (idx < n){
    split2(a[idx], ahi[idx], alo[idx]);
    split2(b[idx], bhi[idx], blo[idx]);
  }
}

// ---------------- MFMA GEMM: C[M x N] = A[M x K](f32) @ W[N x K](f32)^T + bias ----------------
struct GemmJob {
  const float* A; const float* W; const float* bias;
  float* C; int N; int K;
};
struct GemmJobs { GemmJob j[6]; };

__global__ __launch_bounds__(256) void k_gemm(GemmJobs jobs){
  const GemmJob J = jobs.j[blockIdx.z];
  const int tid = threadIdx.x;
  const int lane = tid & 63, w = tid >> 6;
  const int l15 = lane & 15, q = lane >> 4;
  const int n0 = blockIdx.x * 64;
  if (n0 >= J.N) return;
  const int K = J.K;
  const long mrow = blockIdx.y*64 + w*16 + l15;
  const float* Arow = J.A + mrow*K;
  floatx4 acc[4];
  #pragma unroll
  for (int t=0;t<4;t++) acc[t] = (floatx4)0.f;
  const int nch = (K+31)>>5;
  for (int kc=0; kc<nch; kc++){
    const int k0 = kc<<5;
    const int kb = k0 + q*8;
    const bool full = (k0+32 <= K);
    float av[8];
    if (full){
      const floatx4 a0 = *(const floatx4*)(Arow+kb);
      const floatx4 a1 = *(const floatx4*)(Arow+kb+4);
      av[0]=a0[0];av[1]=a0[1];av[2]=a0[2];av[3]=a0[3];
      av[4]=a1[0];av[5]=a1[1];av[6]=a1[2];av[7]=a1[3];
    } else {
      #pragma unroll
      for (int j=0;j<8;j++){ const int k=kb+j; av[j] = (k<K)? Arow[k] : 0.f; }
    }
    union { bf16x8 v; unsigned short u[8]; } ahi, alo;
    #pragma unroll
    for (int j=0;j<8;j++) split2(av[j], ahi.u[j], alo.u[j]);
    #pragma unroll
    for (int t=0;t<4;t++){
      const int n = n0 + t*16 + l15;
      const float* Wr = J.W + (long)n*K + kb;
      float wv[8];
      if (full){
        const floatx4 w0 = *(const floatx4*)(Wr);
        const floatx4 w1 = *(const floatx4*)(Wr+4);
        wv[0]=w0[0];wv[1]=w0[1];wv[2]=w0[2];wv[3]=w0[3];
        wv[4]=w1[0];wv[5]=w1[1];wv[6]=w1[2];wv[7]=w1[3];
      } else {
        #pragma unroll
        for (int j=0;j<8;j++){ const int k=kb+j; wv[j] = (k<K)? Wr[j] : 0.f; }
      }
      union { bf16x8 v; unsigned short u[8]; } whi, wlo;
      #pragma unroll
      for (int j=0;j<8;j++) split2(wv[j], whi.u[j], wlo.u[j]);
      acc[t] = __builtin_amdgcn_mfma_f32_16x16x32_bf16(ahi.v, whi.v, acc[t], 0,0,0);
      acc[t] = __builtin_amdgcn_mfma_f32_16x16x32_bf16(ahi.v, wlo.v, acc[t], 0,0,0);
      acc[t] = __builtin_amdgcn_mfma_f32_16x16x32_bf16(alo.v, whi.v, acc[t], 0,0,0);
    }
  }
  const long rbase = blockIdx.y*64 + w*16 + q*4;
  #pragma unroll
  for (int t=0;t<4;t++){
    const int n = n0 + t*16 + l15;
    const float bv = J.bias ? J.bias[n] : 0.f;
    #pragma unroll
    for (int r=0;r<4;r++)
      J.C[(rbase+r)*(long)J.N + n] = acc[t][r] + bv;
  }
}

// ---------------- GRU scan: 768 threads, 2 threads per gate; xt prefetch ----------------
struct GruJob { const float* xg; const float* Whh; const float* bhh; float* out; int ocol; int rev; };
struct GruJobs { GruJob j[4]; };

__global__ __launch_bounds__(768) void k_gru(GruJobs jobs){
  const GruJob J = jobs.j[blockIdx.y];
  const int bi = blockIdx.x;
  const int tid = threadIdx.x;
  const int g = tid >> 1, p = tid & 1;   // gate, half
  __shared__ float h_sh[HH];
  __shared__ float gh_sh[G3];
  __shared__ float xt_sh[G3];
  float wr[64];
  {
    const float* wp = J.Whh + (long)g*HH + p*64;
    #pragma unroll
    for (int k=0;k<64;k+=4){
      const floatx4 t4 = *(const floatx4*)(wp+k);
      wr[k]=t4[0]; wr[k+1]=t4[1]; wr[k+2]=t4[2]; wr[k+3]=t4[3];
    }
  }
  const float bhh = J.bhh[g];
  if (tid < HH) h_sh[tid] = 0.f;
  float hreg = 0.f;
  float xv = 0.f;
  {
    const int t0 = J.rev ? (TT-1) : 0;
    if (tid < G3) xv = J.xg[((long)bi*TT + t0)*G3 + tid];
  }
  __syncthreads();
  for (int t=0;t<TT;t++){
    const int tt = J.rev ? (TT-1-t) : t;
    if (tid < G3) xt_sh[tid] = xv;
    if (t+1 < TT){
      const int tn = J.rev ? (TT-2-t) : (t+1);
      if (tid < G3) xv = J.xg[((long)bi*TT + tn)*G3 + tid];
    }
    float gh = 0.f;
    #pragma unroll
    for (int k=0;k<64;k+=4){
      const floatx4 h4 = *(const floatx4*)&h_sh[p*64 + k];
      gh += wr[k]*h4[0] + wr[k+1]*h4[1] + wr[k+2]*h4[2] + wr[k+3]*h4[3];
    }
    gh += __shfl_xor(gh, 1);
    if (p==0) gh_sh[g] = gh + bhh;
    __syncthreads();
    if (tid < HH){
      const float r = fsigmoid(xt_sh[tid]       + gh_sh[tid]);
      const float z = fsigmoid(xt_sh[tid+HH]    + gh_sh[tid+HH]);
      const float n = ftanh  (xt_sh[tid+2*HH]  + r*gh_sh[tid+2*HH]);
      const float h = (1.f-z)*n + z*hreg;
      hreg = h;
      h_sh[tid] = h;
      J.out[((long)bi*TT + tt)*D2 + J.ocol + tid] = h;
    }
    __syncthreads();
  }
}

// ---------------- block softmax over 160 values (256 threads) ----------------
__device__ inline float block_softmax160(float s, int tid, float* red){
  float m = s;
  #pragma unroll
  for (int o=32;o>0;o>>=1) m = fmaxf(m, __shfl_xor(m,o));
  if ((tid&63)==0) red[tid>>6] = m;
  __syncthreads();
  m = fmaxf(fmaxf(red[0],red[1]), fmaxf(red[2],red[3]));
  const float p = (tid<TT) ? __expf(s-m) : 0.f;
  float t = p;
  #pragma unroll
  for (int o=32;o>0;o>>=1) t += __shfl_xor(t,o);
  if ((tid&63)==0) red[4+(tid>>6)] = t;
  __syncthreads();
  const float sum = red[4]+red[5]+red[6]+red[7];
  return p / sum;
}

// ---------------- block softmax over 160 values (512 threads) ----------------
__device__ inline float block_softmax160_512(float s, int tid, float* red){
  float m = s;
  #pragma unroll
  for (int o=32;o>0;o>>=1) m = fmaxf(m, __shfl_xor(m,o));
  if ((tid&63)==0) red[tid>>6] = m;
  __syncthreads();
  m = red[0];
  #pragma unroll
  for (int i=1;i<8;i++) m = fmaxf(m, red[i]);
  const float p = (tid<TT) ? __expf(s-m) : 0.f;
  float t = p;
  #pragma unroll
  for (int o=32;o>0;o>>=1) t += __shfl_xor(t,o);
  if ((tid&63)==0) red[8+(tid>>6)] = t;
  __syncthreads();
  float sum = red[8];
  #pragma unroll
  for (int i=1;i<8;i++) sum += red[8+i];
  return p / sum;
}

// ---------------- pairwise product attention (dot & self) via MFMA + LDS pipeline ----------------
// score[b,c,t] = sum_h V[h] * tanh( sum_d (W[h,d]*Q[c,d]) * P[t,d] )
// 512 threads = 8 waves; wave w owns h-rows [w*16, w*16+16) -> acc = 40 AGPR/wave.
// P hi/lo staged in double-buffered LDS; W + next P chunk prefetched into regs.
struct PairJob { const unsigned short* Phi; const unsigned short* Plo;
                 const float* Q; const float* W; const float* V; float* a_out; };

__global__ __launch_bounds__(512) void k_pairattn(PairJob j0, PairJob j1){
  const PairJob J = blockIdx.z ? j1 : j0;
  const int b = blockIdx.y, c = blockIdx.x;
  const int tid = threadIdx.x;
  const int lane = tid & 63, w = tid >> 6;    // 8 waves
  const int l15 = lane & 15, q = lane >> 4;
  __shared__ unsigned short Pb[2*2*160*PSTR]; // [buf][hl][t][PSTR]
  __shared__ float Qs[D2];
  __shared__ float sc_sh[TT];
  __shared__ float red[16];
  if (tid < D2) Qs[tid] = J.Q[((long)b*TT + c)*D2 + tid];
  if (tid < TT) sc_sh[tid] = 0.f;
  const long pbase = (long)b*TT*D2;

  // per-thread staging indices (5 x uint2 = 20480 B per chunk)
  int s_hl[5], s_t[5], s_d4[5];
  #pragma unroll
  for (int r=0;r<5;r++){
    const int idx = tid + r*512;
    const int hl = (idx >= 1280) ? 1 : 0;
    const int e4 = idx - hl*1280;
    s_hl[r] = hl; s_t[r] = e4 >> 3; s_d4[r] = e4 & 7;
  }
  uint2 stg[5];
  #pragma unroll
  for (int r=0;r<5;r++){
    const unsigned short* src = (s_hl[r] ? J.Plo : J.Phi) + pbase + (long)s_t[r]*D2 + 0*32 + s_d4[r]*4;
    stg[r] = *(const uint2*)src;
  }
  // W prefetch for kc=0 (this wave-lane's h-row segment)
  const float* Wbase = J.W + (long)(w*16 + l15)*D2;
  floatx4 wv0 = *(const floatx4*)(Wbase + q*8);
  floatx4 wv1 = *(const floatx4*)(Wbase + q*8 + 4);
  // write chunk 0 to buf 0
  #pragma unroll
  for (int r=0;r<5;r++)
    *(uint2*)&Pb[((0*2 + s_hl[r])*160 + s_t[r])*PSTR + s_d4[r]*4] = stg[r];
  __syncthreads();

  floatx4 acc[10];
  #pragma unroll
  for (int nt=0;nt<10;nt++) acc[nt] = (floatx4)0.f;

  for (int kc=0; kc<8; kc++){
    const floatx4 wc0 = wv0, wc1 = wv1;
    if (kc < 7){
      wv0 = *(const floatx4*)(Wbase + (kc+1)*32 + q*8);
      wv1 = *(const floatx4*)(Wbase + (kc+1)*32 + q*8 + 4);
      #pragma unroll
      for (int r=0;r<5;r++){
        const unsigned short* src = (s_hl[r] ? J.Plo : J.Phi) + pbase + (long)s_t[r]*D2 + (kc+1)*32 + s_d4[r]*4;
        stg[r] = *(const uint2*)src;
      }
    }
    const int d0 = kc*32 + q*8;
    const floatx4 q0 = *(const floatx4*)&Qs[d0];
    const floatx4 q1 = *(const floatx4*)&Qs[d0+4];
    union { bf16x8 v; unsigned short u[8]; } ah, al;
    #pragma unroll
    for (int j=0;j<4;j++){
      split2(wc0[j]*q0[j], ah.u[j],   al.u[j]);
      split2(wc1[j]*q1[j], ah.u[4+j], al.u[4+j]);
    }
    const int buf = kc & 1;
    #pragma unroll
    for (int nt=0;nt<10;nt++){
      const int t = nt*16 + l15;
      union { bf16x8 v; } bh, bl;
      bh.v = *(const bf16x8*)&Pb[((buf*2+0)*160 + t)*PSTR + q*8];
      bl.v = *(const bf16x8*)&Pb[((buf*2+1)*160 + t)*PSTR + q*8];
      acc[nt] = __builtin_amdgcn_mfma_f32_16x16x32_bf16(ah.v, bh.v, acc[nt], 0,0,0);
      acc[nt] = __builtin_amdgcn_mfma_f32_16x16x32_bf16(ah.v, bl.v, acc[nt], 0,0,0);
      acc[nt] = __builtin_amdgcn_mfma_f32_16x16x32_bf16(al.v, bh.v, acc[nt], 0,0,0);
    }
    if (kc < 7){
      const int nbuf = 1 - buf;
      #pragma unroll
      for (int r=0;r<5;r++)
        *(uint2*)&Pb[((nbuf*2 + s_hl[r])*160 + s_t[r])*PSTR + s_d4[r]*4] = stg[r];
      __syncthreads();
    }
  }

  float vreg[4];
  #pragma unroll
  for (int r=0;r<4;r++) vreg[r] = J.V[w*16 + q*4 + r];
  #pragma unroll
  for (int nt=0;nt<10;nt++){
    float pp = 0.f;
    #pragma unroll
    for (int r=0;r<4;r++) pp += vreg[r]*ftanh(acc[nt][r]);
    pp += __shfl_xor(pp,16);
    pp += __shfl_xor(pp,32);
    if (q==0) atomicAdd(&sc_sh[nt*16 + l15], pp);
  }
  __syncthreads();
  const float s = (tid<TT)? sc_sh[tid] : -INFINITY;
  const float a = block_softmax160_512(s, tid, red);
  if (tid < TT) J.a_out[((long)b*TT + c)*TT + tid] = a;
}

// ---------------- additive attentions (concat / minus) ----------------
struct AddJob { const float* up; const float* uc; const float* V; float sgn; float* a_out; };

__global__ __launch_bounds__(256) void k_addattn(AddJob j0, AddJob j1){
  const AddJob J = blockIdx.z ? j1 : j0;
  const int b = blockIdx.y, c = blockIdx.x, tid = threadIdx.x;
  __shared__ float ucc[HH];
  __shared__ float vv[HH];
  __shared__ float red[8];
  if (tid < HH){
    ucc[tid] = J.sgn * J.uc[((long)b*TT + c)*HH + tid];
    vv[tid] = J.V[tid];
  }
  __syncthreads();
  float s = -INFINITY;
  if (tid < TT){
    const float* ur = J.up + ((long)b*TT + tid)*HH;
    float a0 = 0.f;
    #pragma unroll 4
    for (int k=0;k<HH;k++) a0 += vv[k]*ftanh(ur[k]+ucc[k]);
    s = a0;
  }
  const float a = block_softmax160(s, tid, red);
  if (tid < TT) J.a_out[((long)b*TT + c)*TT + tid] = a;
}

// ---------------- bilinear attention ----------------
__global__ __launch_bounds__(256) void k_bilattn(const float* hc, const float* hpWb, float* a_out){
  const int b = blockIdx.y, c = blockIdx.x, tid = threadIdx.x;
  __shared__ float hcc[D2];
  __shared__ float red[8];
  if (tid < D2) hcc[tid] = hc[((long)b*TT + c)*D2 + tid];
  __syncthreads();
  float s = -INFINITY;
  if (tid < TT){
    const float* pr = hpWb + ((long)b*TT + tid)*D2;
    float a0 = 0.f;
    #pragma unroll 4
    for (int k=0;k<D2;k++) a0 += hcc[k]*pr[k];
    s = a0;
  }
  const float a = block_softmax160(s, tid, red);
  if (tid < TT) a_out[((long)b*TT + c)*TT + tid] = a;
}

// ---------------- rep build ----------------
__global__ __launch_bounds__(256) void k_rep(const float* hp, const float* hc,
    const float* acat, const float* abil, const float* adot, const float* amin, const float* aself,
    float* aggin){
  const int b = blockIdx.y, c = blockIdx.x, tid = threadIdx.x;
  __shared__ float a5[5][TT];
  {
    const long base = ((long)b*TT + c)*TT;
    for (int i=tid;i<5*TT;i+=256){
      const int which = i/TT, t = i - which*TT;
      const float* p = which==0? acat : which==1? abil : which==2? adot : which==3? amin : aself;
      a5[which][t] = p[base + t];
    }
  }
  __syncthreads();
  const float* hpb = hp + (long)b*TT*D2 + tid;
  const float* hcb = hc + (long)b*TT*D2 + tid;
  float r0=0.f,r1=0.f,r2=0.f,r3=0.f,r4=0.f;
  for (int t=0;t<TT;t++){
    const float vp = hpb[(long)t*D2];
    const float vc = hcb[(long)t*D2];
    r0 += a5[0][t]*vp;
    r1 += a5[1][t]*vp;
    r2 += a5[2][t]*vp;
    r3 += a5[3][t]*vp;
    r4 += a5[4][t]*vc;
  }
  float* o = aggin + ((long)b*TT + c)*(6*D2);
  o[tid]        = hc[((long)b*TT + c)*D2 + tid];
  o[D2 + tid]   = r4;
  o[2*D2 + tid] = r0;
  o[3*D2 + tid] = r2;
  o[4*D2 + tid] = r1;
  o[5*D2 + tid] = r3;
}

// ---------------- tail1 ----------------
__global__ __launch_bounds__(256) void k_tail1(const float* upP, const float* Vp,
    const float* hp, float* rp){
  const int b = blockIdx.x, tid = threadIdx.x;
  __shared__ float vv[HH];
  __shared__ float ap_sh[TT];
  __shared__ float red[8];
  if (tid<HH) vv[tid] = Vp[tid];
  __syncthreads();
  float s = -INFINITY;
  if (tid<TT){
    const float* ur = upP + ((long)b*TT + tid)*HH;
    float a0=0.f;
    #pragma unroll 4
    for (int k=0;k<HH;k++) a0 += vv[k]*ftanh(ur[k]);
    s = a0;
  }
  const float a = block_softmax160(s, tid, red);
  if (tid<TT) ap_sh[tid] = a;
  __syncthreads();
  float acc = 0.f;
  const float* hpb = hp + (long)b*TT*D2 + tid;
  for (int t=0;t<TT;t++) acc += ap_sh[t]*hpb[(long)t*D2];
  rp[b*D2 + tid] = acc;
}

// ---------------- tail2 ----------------
__global__ __launch_bounds__(256) void k_tail2(const float* aggW1, const float* agg, const float* rp,
    const float* W2, const float* Vv, const float* Wout, const float* bout,
    float* out){
  const int b = blockIdx.x, tid = threadIdx.x;
  __shared__ float rpw[HH];
  __shared__ float ac_sh[TT];
  __shared__ float rc_sh[D2];
  __shared__ float red[8];
  if (tid < HH){
    float a0=0.f;
    const float* wr2 = W2 + (long)tid*D2;
    const float* rr = rp + b*D2;
    for (int d=0; d<D2; d++) a0 += wr2[d]*rr[d];
    rpw[tid] = a0;
  }
  __syncthreads();
  float s = -INFINITY;
  if (tid < TT){
    const float* ar = aggW1 + ((long)b*TT + tid)*HH;
    float a0=0.f;
    for (int k=0;k<HH;k++) a0 += Vv[k]*(ar[k] + rpw[k]);
    s = a0;
  }
  const float a = block_softmax160(s, tid, red);
  if (tid < TT) ac_sh[tid] = a;
  __syncthreads();
  float rc=0.f;
  const float* ab = agg + (long)b*TT*D2 + tid;
  for (int t=0;t<TT;t++) rc += ac_sh[t]*ab[(long)t*D2];
  rc_sh[tid] = rc;
  __syncthreads();
  if (tid < 2){
    float o = bout[tid];
    const float* wr = Wout + (long)tid*D2;
    for (int d=0; d<D2; d++) o += wr[d]*rc_sh[d];
    out[b*2 + tid] = o;
  }
}

extern "C" void kernel_launch(void* const* d_in, const int* in_sizes, int n_in,
                              void* d_out, int out_size, void* d_ws, size_t ws_size,
                              hipStream_t stream){
  (void)in_sizes; (void)n_in; (void)out_size; (void)ws_size;
  const int* ta = (const int*)d_in[0];
  const int* tb = (const int*)d_in[1];
  const float* emb = (const float*)d_in[2];
  #define F32(i) ((const float*)d_in[i])

  float* ws = (float*)d_ws;
  float* ep    = ws;                 // 8*160*300
  float* ec    = ep    + 384000;
  float* xg_pf = ec    + 384000;     // 8*160*384 each; reused by agg stage later
  float* xg_pb = xg_pf + 491520;
  float* xg_cf = xg_pb + 491520;
  float* xg_cb = xg_cf + 491520;
  float* hp    = xg_cb + 491520;     // 8*160*256
  float* hc    = hp    + 327680;
  float* up1   = hc    + 327680;     // 8*160*128 each
  float* uc2   = up1   + 163840;
  float* ump   = uc2   + 163840;
  float* umc   = ump   + 163840;
  float* upP   = umc   + 163840;
  float* hpWb  = upP   + 163840;     // 8*160*256
  float* acat  = hpWb  + 327680;     // 8*160*160 each
  float* abil  = acat  + 204800;
  float* adot  = abil  + 204800;
  float* amin  = adot  + 204800;
  float* aself = amin  + 204800;
  float* aggin = aself + 204800;     // 8*160*1536
  float* rp    = aggin + 1966080;    // 8*256
  unsigned short* hp_hi = (unsigned short*)(rp + 2048);   // 327680 u16 each
  unsigned short* hp_lo = hp_hi + 327680;
  unsigned short* hc_hi = hp_lo + 327680;
  unsigned short* hc_lo = hc_hi + 327680;
  // dead-buffer reuse for the agg stage:
  float* xg_af = xg_pf;              // dead after p/c GRU
  float* xg_ab = xg_pb;
  float* agg   = xg_cf;              // 327680 <= 491520
  float* aggW1 = xg_cb;              // 163840 <= 491520

  // 1) embedding gather
  k_embed<<<dim3(3000), dim3(256), 0, stream>>>(ta, tb, emb, ep, ec);

  // 2) xg = x @ Wih^T + bih for p/c  (M=1280, N=384, K=300)
  GemmJobs ja = {};
  ja.j[0] = {ep, F32(3),  F32(5),  xg_pf, 384, 300};
  ja.j[1] = {ep, F32(7),  F32(9),  xg_pb, 384, 300};
  ja.j[2] = {ec, F32(11), F32(13), xg_cf, 384, 300};
  ja.j[3] = {ec, F32(15), F32(17), xg_cb, 384, 300};
  k_gemm<<<dim3(6,20,4), dim3(256), 0, stream>>>(ja);

  // 3) p/c GRU scans
  GruJobs gj = {};
  gj.j[0] = {xg_pf, F32(4),  F32(6),  hp, 0,   0};
  gj.j[1] = {xg_pb, F32(8),  F32(10), hp, 128, 1};
  gj.j[2] = {xg_cf, F32(12), F32(14), hc, 0,   0};
  gj.j[3] = {xg_cb, F32(16), F32(18), hc, 128, 1};
  k_gru<<<dim3(8,4), dim3(768), 0, stream>>>(gj);

  // 3b) hi/lo split of hp & hc for pairattn B-operands
  k_splitarr<<<dim3(1280), dim3(256), 0, stream>>>(hp, hc, 327680, hp_hi, hp_lo, hc_hi, hc_lo);

  // 4) projection GEMMs (N=128 or 256, K=256)
  GemmJobs jb = {};
  jb.j[0] = {hp, F32(27), nullptr, up1,  128, 256};
  jb.j[1] = {hc, F32(28), nullptr, uc2,  128, 256};
  jb.j[2] = {hp, F32(33), nullptr, ump,  128, 256};
  jb.j[3] = {hc, F32(33), nullptr, umc,  128, 256};
  jb.j[4] = {hp, F32(37), nullptr, upP,  128, 256};
  jb.j[5] = {hp, F32(30), nullptr, hpWb, 256, 256};
  k_gemm<<<dim3(4,20,6), dim3(256), 0, stream>>>(jb);

  // 5) dot & self attentions (MFMA, LDS double-buffered pipeline)
  PairJob pd  = {hp_hi, hp_lo, hc, F32(31), F32(32), adot};
  PairJob psf = {hc_hi, hc_lo, hc, F32(35), F32(36), aself};
  k_pairattn<<<dim3(160,8,2), dim3(512), 0, stream>>>(pd, psf);

  // 6) concat & minus attentions
  AddJob ac_ = {up1, uc2, F32(29),  1.f, acat};
  AddJob am_ = {ump, umc, F32(34), -1.f, amin};
  k_addattn<<<dim3(160,8,2), dim3(256), 0, stream>>>(ac_, am_);

  // 7) bilinear attention
  k_bilattn<<<dim3(160,8), dim3(256), 0, stream>>>(hc, hpWb, abil);

  // 8) ap/rp pooling
  k_tail1<<<dim3(8), dim3(256), 0, stream>>>(upP, F32(38), hp, rp);

  // 9) weighted reps -> agg_in
  k_rep<<<dim3(160,8), dim3(256), 0, stream>>>(hp, hc, acat, abil, adot, amin, aself, aggin);

  // 10) agg xg GEMMs (M=1280, N=384, K=1536)
  GemmJobs jc = {};
  jc.j[0] = {aggin, F32(19), F32(21), xg_af, 384, 1536};
  jc.j[1] = {aggin, F32(23), F32(25), xg_ab, 384, 1536};
  k_gemm<<<dim3(6,20,2), dim3(256), 0, stream>>>(jc);

  // 11) agg GRU scans
  GruJobs gja = {};
  gja.j[0] = {xg_af, F32(20), F32(22), agg, 0,   0};
  gja.j[1] = {xg_ab, F32(24), F32(26), agg, 128, 1};
  k_gru<<<dim3(8,2), dim3(768), 0, stream>>>(gja);

  // 12) agg @ W1^T (N=128, K=256)
  GemmJobs jd = {};
  jd.j[0] = {agg, F32(39), nullptr, aggW1, 128, 256};
  k_gemm<<<dim3(2,20,1), dim3(256), 0, stream>>>(jd);

  // 13) final scores + output
  k_tail2<<<dim3(8), dim3(256), 0, stream>>>(aggW1, agg, rp, F32(40), F32(41), F32(42), F32(43),
                                             (float*)d_out);
  #undef F32
}